// Round 8
// baseline (390.927 us; speedup 1.0000x reference)
//
#include <hip/hip_runtime.h>
#include <hip/hip_bf16.h>
#include <cstdint>
#include <cstddef>

#define D 768
#define BATCH 8
#define LC 2048
#define LQ 1024
#define SCALE 0.03608439182435161f /* 1/sqrt(768) */

typedef __attribute__((ext_vector_type(8))) short short8;
typedef __attribute__((ext_vector_type(4))) float floatx4;

__device__ __forceinline__ short f2bf(float f) {
    union { float f; uint32_t u; } v; v.f = f;
    uint32_t r = v.u + 0x7fffu + ((v.u >> 16) & 1u);
    return (short)(r >> 16);
}

// ---- async global->LDS, 16B per lane ----
__device__ __forceinline__ void gl_lds16(const short* g, short* l) {
    __builtin_amdgcn_global_load_lds(
        reinterpret_cast<const __attribute__((address_space(1))) unsigned int*>(
            reinterpret_cast<uintptr_t>(g)),
        reinterpret_cast<__attribute__((address_space(3))) unsigned int*>(
            reinterpret_cast<uintptr_t>(l)),
        16, 0, 0);
}

// ================= 128x256 core (unchanged, for gemm1) =================
__device__ __forceinline__ void gemm128x256_loop(
    const short* __restrict__ A, const short* __restrict__ B,
    int lda, int ldb, int K, int m0, int n0,
    short* lds, int tid, floatx4 acc[4][4]) {
    const int lane = tid & 63, l15 = lane & 15, quad = lane >> 4;
    const int w = tid >> 6, wm = w >> 2, wn = w & 3;

    const int ra = tid >> 2, sa = (tid & 3) ^ (ra & 3);
    const short* gA = A + (size_t)(m0 + ra) * lda + sa * 8;
    short* dA = lds + tid * 8;
    const int cb0 = tid, cb1 = tid + 512;
    const int rb0 = cb0 >> 2, sb0 = (cb0 & 3) ^ (rb0 & 3);
    const int rb1 = cb1 >> 2, sb1 = (cb1 & 3) ^ (rb1 & 3);
    const short* gB0 = B + (size_t)(n0 + rb0) * ldb + sb0 * 8;
    const short* gB1 = B + (size_t)(n0 + rb1) * ldb + sb1 * 8;
    short* dB0 = lds + 4096 + cb0 * 8;
    short* dB1 = lds + 4096 + cb1 * 8;

    int aoff[4], boff[4];
#pragma unroll
    for (int mt = 0; mt < 4; ++mt) {
        int r = wm * 64 + mt * 16 + l15;
        aoff[mt] = r * 32 + ((quad ^ (r & 3)) * 8);
    }
#pragma unroll
    for (int nt = 0; nt < 4; ++nt) {
        int r = wn * 64 + nt * 16 + l15;
        boff[nt] = 4096 + r * 32 + ((quad ^ (r & 3)) * 8);
    }

    const int NT = K >> 5;
#define STAGE_A(t, bb) { gl_lds16(gA + (t) * 32, dA + (bb)); }
#define STAGE_B(t, bb) { gl_lds16(gB0 + (t) * 32, dB0 + (bb)); gl_lds16(gB1 + (t) * 32, dB1 + (bb)); }
    STAGE_A(0, 0) STAGE_B(0, 0)
    STAGE_A(1, 12288) STAGE_B(1, 12288)

    for (int kt = 0; kt < NT; ++kt) {
        const int cur = (kt % 3) * 12288;
        const int nxt = ((kt + 2) % 3) * 12288;
        if (kt + 1 < NT) { asm volatile("s_waitcnt vmcnt(3)" ::: "memory"); }
        else             { asm volatile("s_waitcnt vmcnt(0)" ::: "memory"); }
        __builtin_amdgcn_s_barrier();
        __builtin_amdgcn_sched_barrier(0);

        if (kt + 2 < NT) STAGE_A((kt + 2), nxt)

        short8 af[4], bf[4];
#pragma unroll
        for (int mt = 0; mt < 4; ++mt)
            af[mt] = *reinterpret_cast<const short8*>(lds + cur + aoff[mt]);
#pragma unroll
        for (int nt = 0; nt < 2; ++nt)
            bf[nt] = *reinterpret_cast<const short8*>(lds + cur + boff[nt]);
        __builtin_amdgcn_s_setprio(1);
#pragma unroll
        for (int mt = 0; mt < 4; ++mt)
#pragma unroll
            for (int nt = 0; nt < 2; ++nt)
                acc[mt][nt] = __builtin_amdgcn_mfma_f32_16x16x32_bf16(af[mt], bf[nt], acc[mt][nt], 0, 0, 0);
        __builtin_amdgcn_s_setprio(0);

        if (kt + 2 < NT) STAGE_B((kt + 2), nxt)

#pragma unroll
        for (int nt = 2; nt < 4; ++nt)
            bf[nt] = *reinterpret_cast<const short8*>(lds + cur + boff[nt]);
        __builtin_amdgcn_s_setprio(1);
#pragma unroll
        for (int mt = 0; mt < 4; ++mt)
#pragma unroll
            for (int nt = 2; nt < 4; ++nt)
                acc[mt][nt] = __builtin_amdgcn_mfma_f32_16x16x32_bf16(af[mt], bf[nt], acc[mt][nt], 0, 0, 0);
        __builtin_amdgcn_s_setprio(0);
        __builtin_amdgcn_sched_barrier(0);
    }
#undef STAGE_A
#undef STAGE_B
}

// ---------------- fused prep: cast W, ctx copy+cast, qh cast+transpose ----------
__global__ __launch_bounds__(256) void prep_kernel(
    const float* __restrict__ ctx, const float* __restrict__ qh,
    const float* __restrict__ Wf, float* __restrict__ out,
    short* __restrict__ W_b, short* __restrict__ ctx_b,
    short* __restrict__ qh_b, short* __restrict__ qhT) {
    __shared__ float tile[32][33];
    const int tid = threadIdx.x;
    const int bid = blockIdx.x;
    const int gid = bid * 256 + tid;          // grid = 2048 x 256 = 524288 threads

    if (gid < 147456) {
        float4 v = reinterpret_cast<const float4*>(Wf)[gid];
        short4 o;
        o.x = f2bf(v.x); o.y = f2bf(v.y); o.z = f2bf(v.z); o.w = f2bf(v.w);
        reinterpret_cast<short4*>(W_b)[gid] = o;
    }
#pragma unroll
    for (int it = 0; it < 6; ++it) {
        int i = gid + it * 524288;
        int row = i / 192, c4 = i % 192;
        float4 v = reinterpret_cast<const float4*>(ctx)[i];
        reinterpret_cast<float4*>(out)[(size_t)row * 384 + c4] = v;
        short4 o;
        o.x = f2bf(v.x); o.y = f2bf(v.y); o.z = f2bf(v.z); o.w = f2bf(v.w);
        reinterpret_cast<short4*>(ctx_b)[i] = o;
    }
    const int r = tid >> 3, c = (tid & 7) * 4;
#pragma unroll
    for (int it = 0; it < 3; ++it) {
        const int T = bid + it * 2048;
        const int b = T / 768, rem = T % 768;
        const int q0 = (rem / 24) * 32, d0 = (rem % 24) * 32;
        const float4 v = *reinterpret_cast<const float4*>(
            qh + ((size_t)b * LQ + q0 + r) * D + d0 + c);
        tile[r][c] = v.x; tile[r][c + 1] = v.y; tile[r][c + 2] = v.z; tile[r][c + 3] = v.w;
        short4 d;
        d.x = f2bf(v.x); d.y = f2bf(v.y); d.z = f2bf(v.z); d.w = f2bf(v.w);
        *reinterpret_cast<short4*>(qh_b + ((size_t)b * LQ + q0 + r) * D + d0 + c) = d;
        __syncthreads();
        short4 o;
        o.x = f2bf(tile[c][r]); o.y = f2bf(tile[c + 1][r]);
        o.z = f2bf(tile[c + 2][r]); o.w = f2bf(tile[c + 3][r]);
        *reinterpret_cast<short4*>(qhT + ((size_t)b * D + d0 + r) * LQ + q0 + c) = o;
        __syncthreads();
    }
}

// ---------------- GEMM1: query = qh_b * W_b^T + bias -> bf16; 192 blocks -------
__global__ __launch_bounds__(512, 4) void gemm1_kernel(
    const short* __restrict__ A, const short* __restrict__ W,
    const float* __restrict__ bias, short* __restrict__ Q) {
    __shared__ __align__(16) short lds[3 * 12288];  // 72 KiB
    const int nb = (blockIdx.x & 7) * 24 + (blockIdx.x >> 3);
    const int m0 = (nb / 3) * 128, n0 = (nb % 3) * 256;
    const int tid = threadIdx.x;
    const int lane = tid & 63, l15 = lane & 15, quad = lane >> 4;
    const int w = tid >> 6, wm = w >> 2, wn = w & 3;
    floatx4 acc[4][4];
#pragma unroll
    for (int i = 0; i < 4; ++i)
#pragma unroll
        for (int j = 0; j < 4; ++j) { floatx4 z = {0.f, 0.f, 0.f, 0.f}; acc[i][j] = z; }
    gemm128x256_loop(A, W, D, D, D, m0, n0, lds, tid, acc);
    float bv[4];
#pragma unroll
    for (int nt = 0; nt < 4; ++nt) bv[nt] = bias[n0 + wn * 64 + nt * 16 + l15];
#pragma unroll
    for (int mt = 0; mt < 4; ++mt)
#pragma unroll
        for (int rr = 0; rr < 4; ++rr) {
            int row = m0 + wm * 64 + mt * 16 + quad * 4 + rr;
#pragma unroll
            for (int nt = 0; nt < 4; ++nt)
                Q[(size_t)row * D + n0 + wn * 64 + nt * 16 + l15] = f2bf(acc[mt][nt][rr] + bv[nt]);
        }
}

// ================= fused attention: S = ctx@query^T, P = mask?exp:0, O = P@qh / rowsum =====
// 256 blocks (batch = bid&7 -> one batch per XCD; 32 row-blocks of 64 ctx rows).
// LDS: ctx[64][768] bf16 persistent (96 KiB, XOR-swizzled 16B slots, slot^=(row&7))
//    + P[64][128] bf16 (16 KiB, same swizzle) + rowsum4[4][64] f32 (1 KiB).
// B operands (query, qhT) read register-direct from global (1.5 MB/batch -> L2-resident).
// Per q-chunk (8 x 128): S-GEMM (24 kt) -> exp/mask/partial row-sum (regs) -> P to LDS
// -> barrier -> PV (4 kt x 12 nt) -> barrier. Each wave's psum covers only its wn-slice
// (32 of 128 cols/chunk) -> cross-wave reduction via rowsum4 BEFORE normalize (r7 bugfix).
#define CTXS 49152
__global__ __launch_bounds__(512, 2) void attn_kernel(
    const short* __restrict__ ctxb, const short* __restrict__ query_b,
    const short* __restrict__ qhT, const int* __restrict__ qmask,
    float* __restrict__ out) {
    __shared__ __align__(16) short lds[CTXS + 8192];  // 112 KiB
    __shared__ float rowsum4[4][64];                  // per-wn partial row sums
    const int tid = threadIdx.x;
    const int b = blockIdx.x & 7;
    const int rowblk = blockIdx.x >> 3;
    const int m0 = rowblk * 64;
    const int lane = tid & 63, l15 = lane & 15, quad = lane >> 4;
    const int w = tid >> 6, wm = w >> 2, wn = w & 3;

    // ---- stage ctx[64][768] -> swizzled LDS (once) ----
    const short* cbase = ctxb + ((size_t)b * LC + m0) * D;
#pragma unroll
    for (int i = 0; i < 12; ++i) {
        int cch = tid + i * 512;
        int row = cch / 96, s = cch - row * 96;
        gl_lds16(cbase + (size_t)row * D + ((s ^ (row & 7)) * 8), lds + cch * 8);
    }

    int abase[2], axor[2], pabase[2];
#pragma unroll
    for (int mt = 0; mt < 2; ++mt) {
        int ar = wm * 32 + mt * 16 + l15;
        abase[mt] = ar * 768; axor[mt] = ar & 7;
        pabase[mt] = CTXS + ar * 128;
    }
    const short* qb = query_b + (size_t)b * LQ * D + (size_t)(wn * 32 + l15) * D + quad * 8;
    const short* qt = qhT + (size_t)b * D * LQ + (size_t)(wn * 192 + l15) * LQ + quad * 8;
    const int* mk = qmask + b * LQ;

    floatx4 oacc[2][12];
#pragma unroll
    for (int i = 0; i < 2; ++i)
#pragma unroll
        for (int j = 0; j < 12; ++j) { floatx4 z = {0.f, 0.f, 0.f, 0.f}; oacc[i][j] = z; }
    float psum[2][4];
#pragma unroll
    for (int i = 0; i < 2; ++i)
#pragma unroll
        for (int j = 0; j < 4; ++j) psum[i][j] = 0.f;

    asm volatile("s_waitcnt vmcnt(0)" ::: "memory");
    __builtin_amdgcn_s_barrier();

    for (int ch = 0; ch < 8; ++ch) {
        const int q0 = ch * 128;
        // ---- S = ctx_tile @ query_chunk^T  (S[64,128], per wave 32x32) ----
        floatx4 sacc[2][2];
#pragma unroll
        for (int i = 0; i < 2; ++i)
#pragma unroll
            for (int j = 0; j < 2; ++j) { floatx4 z = {0.f, 0.f, 0.f, 0.f}; sacc[i][j] = z; }
        const short* qbc = qb + (size_t)q0 * D;
#pragma unroll 8
        for (int kt = 0; kt < 24; ++kt) {
            short8 bf0 = *reinterpret_cast<const short8*>(qbc + kt * 32);
            short8 bf1 = *reinterpret_cast<const short8*>(qbc + 16 * D + kt * 32);
            short8 af0 = *reinterpret_cast<const short8*>(lds + abase[0] + ((kt * 4 + quad) ^ axor[0]) * 8);
            short8 af1 = *reinterpret_cast<const short8*>(lds + abase[1] + ((kt * 4 + quad) ^ axor[1]) * 8);
            sacc[0][0] = __builtin_amdgcn_mfma_f32_16x16x32_bf16(af0, bf0, sacc[0][0], 0, 0, 0);
            sacc[0][1] = __builtin_amdgcn_mfma_f32_16x16x32_bf16(af0, bf1, sacc[0][1], 0, 0, 0);
            sacc[1][0] = __builtin_amdgcn_mfma_f32_16x16x32_bf16(af1, bf0, sacc[1][0], 0, 0, 0);
            sacc[1][1] = __builtin_amdgcn_mfma_f32_16x16x32_bf16(af1, bf1, sacc[1][1], 0, 0, 0);
        }
        // ---- epilogue: mask, exp, partial row-sum (regs), P -> swizzled LDS ----
        bool valid0 = (mk[q0 + wn * 32 + l15] != 0);
        bool valid1 = (mk[q0 + wn * 32 + 16 + l15] != 0);
#pragma unroll
        for (int mt = 0; mt < 2; ++mt)
#pragma unroll
            for (int rr = 0; rr < 4; ++rr) {
                int prow = wm * 32 + mt * 16 + quad * 4 + rr;
                float pv0 = valid0 ? __expf(sacc[mt][0][rr] * SCALE) : 0.f;
                float pv1 = valid1 ? __expf(sacc[mt][1][rr] * SCALE) : 0.f;
                int pc0 = wn * 32 + l15;
                int pc1 = pc0 + 16;
                lds[CTXS + prow * 128 + ((((pc0 >> 3) ^ (prow & 7)) << 3) | (pc0 & 7))] = f2bf(pv0);
                lds[CTXS + prow * 128 + ((((pc1 >> 3) ^ (prow & 7)) << 3) | (pc1 & 7))] = f2bf(pv1);
                float rsum = pv0 + pv1;
#pragma unroll
                for (int off = 1; off < 16; off <<= 1)
                    rsum += __shfl_xor(rsum, off, 64);
                psum[mt][rr] += rsum;   // wave-local partial: this wn's 32 cols of this chunk
            }
        asm volatile("s_waitcnt lgkmcnt(0)" ::: "memory");
        __builtin_amdgcn_sched_barrier(0);
        __builtin_amdgcn_s_barrier();
        __builtin_amdgcn_sched_barrier(0);
        // ---- PV: O += P @ qhT^T  (per wave 32 rows x 192 cols) ----
        const short* qtc = qt + q0;
#pragma unroll
        for (int kt = 0; kt < 4; ++kt) {
            short8 pa0 = *reinterpret_cast<const short8*>(lds + pabase[0] + ((kt * 4 + quad) ^ axor[0]) * 8);
            short8 pa1 = *reinterpret_cast<const short8*>(lds + pabase[1] + ((kt * 4 + quad) ^ axor[1]) * 8);
#pragma unroll
            for (int nt = 0; nt < 12; ++nt) {
                short8 bq = *reinterpret_cast<const short8*>(qtc + (size_t)nt * 16 * LQ + kt * 32);
                oacc[0][nt] = __builtin_amdgcn_mfma_f32_16x16x32_bf16(pa0, bq, oacc[0][nt], 0, 0, 0);
                oacc[1][nt] = __builtin_amdgcn_mfma_f32_16x16x32_bf16(pa1, bq, oacc[1][nt], 0, 0, 0);
            }
        }
        __builtin_amdgcn_sched_barrier(0);
        __builtin_amdgcn_s_barrier();
        __builtin_amdgcn_sched_barrier(0);
    }
    // ---- cross-wave row-sum reduction (r7 BUGFIX: psum is a per-wn partial) ----
    // After the butterfly, all 16 l15-lanes of a quad hold the same partial; one lane
    // per (wave, quad) publishes it. Waves (wm, wn) cover disjoint [wn][wm*32+...] slots.
    if (l15 == 0) {
#pragma unroll
        for (int mt = 0; mt < 2; ++mt)
#pragma unroll
            for (int rr = 0; rr < 4; ++rr)
                rowsum4[wn][wm * 32 + mt * 16 + quad * 4 + rr] = psum[mt][rr];
    }
    __syncthreads();
    // ---- normalize + write out[..., 768:1536] ----
#pragma unroll
    for (int mt = 0; mt < 2; ++mt)
#pragma unroll
        for (int rr = 0; rr < 4; ++rr) {
            int prow = wm * 32 + mt * 16 + quad * 4 + rr;
            int lrow = m0 + prow;
            const float inv = 1.0f / (rowsum4[0][prow] + rowsum4[1][prow] +
                                      rowsum4[2][prow] + rowsum4[3][prow]);
            size_t ro = ((size_t)b * LC + lrow) * 1536 + 768;
#pragma unroll
            for (int nt = 0; nt < 12; ++nt)
                out[ro + wn * 192 + nt * 16 + l15] = oacc[mt][nt][rr] * inv;
        }
}

extern "C" void kernel_launch(void* const* d_in, const int* in_sizes, int n_in,
                              void* d_out, int out_size, void* d_ws, size_t ws_size,
                              hipStream_t stream) {
    const float* ctx = (const float*)d_in[0];
    const float* qh = (const float*)d_in[2];
    const int* qmask = (const int*)d_in[3];
    const float* Wf = (const float*)d_in[4];
    const float* bias = (const float*)d_in[5];
    float* out = (float*)d_out;

    char* ws = (char*)d_ws;
    short* W_b     = (short*)(ws);                  //  1,179,648 B
    short* query_b = (short*)(ws + 1179648);        // 12,582,912 B
    short* qhT     = (short*)(ws + 13762560);       // 12,582,912 B
    short* ctx_b   = (short*)(ws + 26345472);       // 25,165,824 B
    short* qh_b    = (short*)(ws + 51511296);       // 12,582,912 B (P/sums no longer exist)

    prep_kernel<<<2048, 256, 0, stream>>>(ctx, qh, Wf, out, W_b, ctx_b, qh_b, qhT);
    gemm1_kernel<<<192, 512, 0, stream>>>(qh_b, W_b, bias, query_b);
    attn_kernel<<<256, 512, 0, stream>>>(ctx_b, query_b, qhT, qmask, out);
}